// Round 2
// baseline (174.441 us; speedup 1.0000x reference)
//
#include <hip/hip_runtime.h>
#include <hip/hip_bf16.h>

#define N 8192
#define D 128
#define HALF_N 4096
// z is stored pre-scaled by sqrt(1/T) so acc = z.z^T is already sim (=10*cos).
#define SQRT_SCALE 3.16227766016838f

#define BLOCK_ROWS 256   // 4 waves * 64 rows each
#define COLS_PER_ITER 64
#define COL_SPLITS 32
#define COLS_PER_BLOCK (N / COL_SPLITS)          // 256
#define ITERS (COLS_PER_BLOCK / COLS_PER_ITER)   // 4
#define LDS_STRIDE 136   // 128 + 8 pad: row stride = 68 dwords -> uniform bank spread

typedef short frag8 __attribute__((ext_vector_type(8)));
typedef float f32x4 __attribute__((ext_vector_type(4)));

// ws layout (floats): pos[N] | psums[COL_SPLITS][N] | acc0 | pad | z (bf16)
#define OFF_POS    0
#define OFF_PSUMS  (N)
#define OFF_ACC    (N + COL_SPLITS * N)
#define OFF_Z_BYTES ((OFF_ACC + 64) * 4)   // 16B-aligned

__device__ __forceinline__ unsigned short f2bf(float f) {
    unsigned int u = __float_as_uint(f);
    u += 0x7FFFu + ((u >> 16) & 1u);
    return (unsigned short)(u >> 16);
}

// K1: z = sqrt(10) * x / max(||x||, eps)  (bf16); zero the scalar accumulator.
__global__ __launch_bounds__(64) void k_normalize(const float* __restrict__ x,
                                                  unsigned short* __restrict__ z,
                                                  float* __restrict__ acc0) {
    const int row = blockIdx.x;
    const int lane = threadIdx.x;
    float2 v = ((const float2*)x)[row * 64 + lane];
    float s = v.x * v.x + v.y * v.y;
    #pragma unroll
    for (int m = 32; m >= 1; m >>= 1) s += __shfl_xor(s, m);
    float inv = SQRT_SCALE / fmaxf(sqrtf(s), 1e-8f);
    ushort2 o;
    o.x = f2bf(v.x * inv);
    o.y = f2bf(v.y * inv);
    ((ushort2*)z)[row * 64 + lane] = o;
    if (row == 0 && lane == 0) acc0[0] = 0.0f;
}

// K2: fused z.z^T + exp + per-row partial sums (deterministic per-split stores).
// Diag mask / pos capture only ever occur on the block-diagonal 64x64 tile
// (local col == local row), i.e. one iteration per wave per kernel for each.
__global__ __launch_bounds__(256, 4) void k_simloss(const unsigned short* __restrict__ z,
                                                    float* __restrict__ psums,
                                                    float* __restrict__ pos) {
    __shared__ unsigned short lds[COLS_PER_ITER * LDS_STRIDE];  // 17408 B

    const int tid  = threadIdx.x;
    const int wave = tid >> 6;
    const int lane = tid & 63;
    const int l15  = lane & 15;
    const int quad = lane >> 4;
    const int wrow = blockIdx.x * BLOCK_ROWS + wave * 64;
    const int colbase0 = blockIdx.y * COLS_PER_BLOCK;
    const int posbase  = (wrow + HALF_N) & (N - 1);

    // A fragments: 4 row-stripes of 16 x K=128, register-resident.
    frag8 a[4][4];
    #pragma unroll
    for (int s = 0; s < 4; ++s) {
        const uint4* p = (const uint4*)&z[(wrow + s * 16 + l15) * D + quad * 8];
        #pragma unroll
        for (int q = 0; q < 4; ++q) {
            uint4 t = p[q * 4];
            a[s][q] = *(frag8*)&t;
        }
    }

    float sums[4][4];
    #pragma unroll
    for (int s = 0; s < 4; ++s)
        #pragma unroll
        for (int r = 0; r < 4; ++r) sums[s][r] = 0.0f;

    for (int it = 0; it < ITERS; ++it) {
        const int colbase = colbase0 + it * COLS_PER_ITER;
        __syncthreads();
        #pragma unroll
        for (int u = 0; u < 4; ++u) {
            int idx = u * 256 + tid;
            int r   = idx >> 4;
            int c8  = idx & 15;
            uint4 t = *(const uint4*)&z[(colbase + r) * D + c8 * 8];
            *(uint4*)&lds[r * LDS_STRIDE + c8 * 8] = t;
        }
        __syncthreads();

        const bool isDiag = (colbase == wrow);
        const bool isPos  = (colbase == posbase);
        const unsigned short* lp = &lds[l15 * LDS_STRIDE + quad * 8];

        #pragma unroll
        for (int c = 0; c < 4; ++c) {
            f32x4 acc[4];
            #pragma unroll
            for (int s = 0; s < 4; ++s) acc[s] = (f32x4){0.f, 0.f, 0.f, 0.f};
            #pragma unroll
            for (int q = 0; q < 4; ++q) {
                frag8 b = *(const frag8*)(lp + c * 16 * LDS_STRIDE + q * 32);
                #pragma unroll
                for (int s = 0; s < 4; ++s)
                    acc[s] = __builtin_amdgcn_mfma_f32_16x16x32_bf16(a[s][q], b, acc[s], 0, 0, 0);
            }
            if (isDiag | isPos) {
                // special tile: local diagonal element lives at c==s, l15==quad*4+r
                #pragma unroll
                for (int s = 0; s < 4; ++s)
                    #pragma unroll
                    for (int r = 0; r < 4; ++r) {
                        float v = acc[s][r];
                        float e = __expf(v);
                        if (c == s) {  // compile-time
                            bool hit = (l15 == quad * 4 + r);
                            if (isDiag && hit) e = 0.0f;
                            if (isPos  && hit) pos[wrow + s * 16 + quad * 4 + r] = v;
                        }
                        sums[s][r] += e;
                    }
            } else {
                #pragma unroll
                for (int s = 0; s < 4; ++s)
                    #pragma unroll
                    for (int r = 0; r < 4; ++r)
                        sums[s][r] += __expf(acc[s][r]);
            }
        }
    }

    // Reduce each row-sum across the 16 lanes holding that row; one store per row.
    #pragma unroll
    for (int s = 0; s < 4; ++s)
        #pragma unroll
        for (int r = 0; r < 4; ++r) {
            float v = sums[s][r];
            v += __shfl_xor(v, 1);
            v += __shfl_xor(v, 2);
            v += __shfl_xor(v, 4);
            v += __shfl_xor(v, 8);
            if (l15 == 0)
                psums[blockIdx.y * N + wrow + s * 16 + quad * 4 + r] = v;
        }
}

// K3a: per-row loss = log(sum of 32 partials) - pos; block-reduce; atomic into acc0.
__global__ __launch_bounds__(1024) void k_rowloss(const float* __restrict__ psums,
                                                  const float* __restrict__ pos,
                                                  float* __restrict__ acc0) {
    const int row = blockIdx.x * 1024 + threadIdx.x;
    float t = 0.0f;
    #pragma unroll
    for (int s = 0; s < COL_SPLITS; ++s) t += psums[s * N + row];
    float loss = __logf(t) - pos[row];
    #pragma unroll
    for (int m = 32; m >= 1; m >>= 1) loss += __shfl_xor(loss, m);
    __shared__ float p[16];
    if ((threadIdx.x & 63) == 0) p[threadIdx.x >> 6] = loss;
    __syncthreads();
    if (threadIdx.x == 0) {
        float s = 0.0f;
        #pragma unroll
        for (int w = 0; w < 16; ++w) s += p[w];
        atomicAdd(acc0, s);
    }
}

// K3b: mean.
__global__ void k_final(const float* __restrict__ acc0, float* __restrict__ out) {
    out[0] = acc0[0] * (1.0f / N);
}

extern "C" void kernel_launch(void* const* d_in, const int* in_sizes, int n_in,
                              void* d_out, int out_size, void* d_ws, size_t ws_size,
                              hipStream_t stream) {
    const float* x = (const float*)d_in[0];
    float* wsf   = (float*)d_ws;
    float* pos   = wsf + OFF_POS;
    float* psums = wsf + OFF_PSUMS;
    float* acc0  = wsf + OFF_ACC;
    unsigned short* z = (unsigned short*)((char*)d_ws + OFF_Z_BYTES);

    k_normalize<<<N, 64, 0, stream>>>(x, z, acc0);
    dim3 g2(N / BLOCK_ROWS, COL_SPLITS);  // (32, 32) = 1024 blocks
    k_simloss<<<g2, 256, 0, stream>>>(z, psums, pos);
    k_rowloss<<<N / 1024, 1024, 0, stream>>>(psums, pos, acc0);
    k_final<<<1, 1, 0, stream>>>(acc0, (float*)d_out);
}

// Round 3
// 84.010 us; speedup vs baseline: 2.0764x; 2.0764x over previous
//
#include <hip/hip_runtime.h>
#include <hip/hip_bf16.h>

#define N 8192
#define D 128
#define HALF_N 4096
// z pre-scaled by sqrt(10 * log2(e)) so acc = z.z^T is sim in log2 domain:
// exp(sim) == exp2(acc). pos (= sim) recovered as acc * ln2 on its single tile.
#define SQRT_SCALE_LOG2E 3.79828236f
#define LN2 0.693147180559945f

#define BLOCK_ROWS 256   // 4 waves * 64 rows each
#define COLS_PER_ITER 64
#define COL_SPLITS 16
#define COLS_PER_BLOCK (N / COL_SPLITS)          // 512
#define ITERS (COLS_PER_BLOCK / COLS_PER_ITER)   // 8
#define LDS_STRIDE 136   // 128 + 8 pad

typedef short frag8 __attribute__((ext_vector_type(8)));
typedef float f32x4 __attribute__((ext_vector_type(4)));

// ws layout (floats): pos[N] | psums[COL_SPLITS][N] | acc0 | pad | z (bf16)
#define OFF_POS    0
#define OFF_PSUMS  (N)
#define OFF_ACC    (N + COL_SPLITS * N)
#define OFF_Z_BYTES ((OFF_ACC + 64) * 4)

__device__ __forceinline__ unsigned short f2bf(float f) {
    unsigned int u = __float_as_uint(f);
    u += 0x7FFFu + ((u >> 16) & 1u);
    return (unsigned short)(u >> 16);
}

// K1: z = sqrt(10*log2e) * x / max(||x||, eps)  (bf16); zero scalar acc.
// 256 threads = 4 rows per block.
__global__ __launch_bounds__(256) void k_normalize(const float* __restrict__ x,
                                                   unsigned short* __restrict__ z,
                                                   float* __restrict__ acc0) {
    const int row  = blockIdx.x * 4 + (threadIdx.x >> 6);
    const int lane = threadIdx.x & 63;
    float2 v = ((const float2*)x)[row * 64 + lane];
    float s = v.x * v.x + v.y * v.y;
    #pragma unroll
    for (int m = 32; m >= 1; m >>= 1) s += __shfl_xor(s, m);
    float inv = SQRT_SCALE_LOG2E / fmaxf(sqrtf(s), 1e-8f);
    ushort2 o;
    o.x = f2bf(v.x * inv);
    o.y = f2bf(v.y * inv);
    ((ushort2*)z)[row * 64 + lane] = o;
    if (blockIdx.x == 0 && threadIdx.x == 0) acc0[0] = 0.0f;
}

// K2: fused z.z^T + exp2 + per-row partial sums.
__global__ __launch_bounds__(256, 2) void k_simloss(const unsigned short* __restrict__ z,
                                                    float* __restrict__ psums,
                                                    float* __restrict__ pos) {
    __shared__ unsigned short lds[COLS_PER_ITER * LDS_STRIDE];  // 17408 B

    const int tid  = threadIdx.x;
    const int wave = tid >> 6;
    const int lane = tid & 63;
    const int l15  = lane & 15;
    const int quad = lane >> 4;
    const int wrow = blockIdx.x * BLOCK_ROWS + wave * 64;
    const int colbase0 = blockIdx.y * COLS_PER_BLOCK;
    const int posbase  = (wrow + HALF_N) & (N - 1);

    // A fragments: 4 row-stripes of 16 x K=128, register-resident (64 VGPRs).
    frag8 a[4][4];
    #pragma unroll
    for (int s = 0; s < 4; ++s) {
        const uint4* p = (const uint4*)&z[(wrow + s * 16 + l15) * D + quad * 8];
        #pragma unroll
        for (int q = 0; q < 4; ++q) {
            uint4 t = p[q * 4];
            a[s][q] = *(frag8*)&t;
        }
    }

    float sums[4][4];
    #pragma unroll
    for (int s = 0; s < 4; ++s)
        #pragma unroll
        for (int r = 0; r < 4; ++r) sums[s][r] = 0.0f;

    for (int it = 0; it < ITERS; ++it) {
        const int colbase = colbase0 + it * COLS_PER_ITER;
        __syncthreads();
        #pragma unroll
        for (int u = 0; u < 4; ++u) {
            int idx = u * 256 + tid;
            int r   = idx >> 4;
            int c8  = idx & 15;
            uint4 t = *(const uint4*)&z[(colbase + r) * D + c8 * 8];
            *(uint4*)&lds[r * LDS_STRIDE + c8 * 8] = t;
        }
        __syncthreads();

        const bool isDiag = (colbase == wrow);
        const bool isPos  = (colbase == posbase);
        const unsigned short* lp = &lds[l15 * LDS_STRIDE + quad * 8];

        #pragma unroll
        for (int c = 0; c < 4; ++c) {
            f32x4 acc[4];
            #pragma unroll
            for (int s = 0; s < 4; ++s) acc[s] = (f32x4){0.f, 0.f, 0.f, 0.f};
            #pragma unroll
            for (int q = 0; q < 4; ++q) {
                frag8 b = *(const frag8*)(lp + c * 16 * LDS_STRIDE + q * 32);
                #pragma unroll
                for (int s = 0; s < 4; ++s)
                    acc[s] = __builtin_amdgcn_mfma_f32_16x16x32_bf16(a[s][q], b, acc[s], 0, 0, 0);
            }
            if (isDiag | isPos) {
                // special tile: local diagonal element at c==s, l15==quad*4+r
                #pragma unroll
                for (int s = 0; s < 4; ++s)
                    #pragma unroll
                    for (int r = 0; r < 4; ++r) {
                        float v = acc[s][r];
                        float e = __builtin_amdgcn_exp2f(v);
                        if (c == s) {  // compile-time
                            bool hit = (l15 == quad * 4 + r);
                            if (isDiag && hit) e = 0.0f;
                            if (isPos  && hit) pos[wrow + s * 16 + quad * 4 + r] = v * LN2;
                        }
                        sums[s][r] += e;
                    }
            } else {
                #pragma unroll
                for (int s = 0; s < 4; ++s)
                    #pragma unroll
                    for (int r = 0; r < 4; ++r)
                        sums[s][r] += __builtin_amdgcn_exp2f(acc[s][r]);
            }
        }
    }

    // Reduce each row-sum across the 16 lanes holding that row; one store per row.
    #pragma unroll
    for (int s = 0; s < 4; ++s)
        #pragma unroll
        for (int r = 0; r < 4; ++r) {
            float v = sums[s][r];
            v += __shfl_xor(v, 1);
            v += __shfl_xor(v, 2);
            v += __shfl_xor(v, 4);
            v += __shfl_xor(v, 8);
            if (l15 == 0)
                psums[blockIdx.y * N + wrow + s * 16 + quad * 4 + r] = v;
        }
}

// K3a: per-row loss = log(sum of partials) - pos; block-reduce; atomic into acc0.
__global__ __launch_bounds__(1024) void k_rowloss(const float* __restrict__ psums,
                                                  const float* __restrict__ pos,
                                                  float* __restrict__ acc0) {
    const int row = blockIdx.x * 1024 + threadIdx.x;
    float t = 0.0f;
    #pragma unroll
    for (int s = 0; s < COL_SPLITS; ++s) t += psums[s * N + row];
    float loss = __logf(t) - pos[row];
    #pragma unroll
    for (int m = 32; m >= 1; m >>= 1) loss += __shfl_xor(loss, m);
    __shared__ float p[16];
    if ((threadIdx.x & 63) == 0) p[threadIdx.x >> 6] = loss;
    __syncthreads();
    if (threadIdx.x == 0) {
        float s = 0.0f;
        #pragma unroll
        for (int w = 0; w < 16; ++w) s += p[w];
        atomicAdd(acc0, s);
    }
}

// K3b: mean.
__global__ void k_final(const float* __restrict__ acc0, float* __restrict__ out) {
    out[0] = acc0[0] * (1.0f / N);
}

extern "C" void kernel_launch(void* const* d_in, const int* in_sizes, int n_in,
                              void* d_out, int out_size, void* d_ws, size_t ws_size,
                              hipStream_t stream) {
    const float* x = (const float*)d_in[0];
    float* wsf   = (float*)d_ws;
    float* pos   = wsf + OFF_POS;
    float* psums = wsf + OFF_PSUMS;
    float* acc0  = wsf + OFF_ACC;
    unsigned short* z = (unsigned short*)((char*)d_ws + OFF_Z_BYTES);

    k_normalize<<<N / 4, 256, 0, stream>>>(x, z, acc0);
    dim3 g2(N / BLOCK_ROWS, COL_SPLITS);  // (32, 16) = 512 blocks -> 2/CU
    k_simloss<<<g2, 256, 0, stream>>>(z, psums, pos);
    k_rowloss<<<N / 1024, 1024, 0, stream>>>(psums, pos, acc0);
    k_final<<<1, 1, 0, stream>>>(acc0, (float*)d_out);
}